// Round 1
// baseline (708.387 us; speedup 1.0000x reference)
//
#include <hip/hip_runtime.h>

// SLAYER 3-layer CUBA SNN on MI355X.
// Layer l: Z[t,b,o] = sum_i W[o,i] * S[b,i,t]  (GEMM, M=(t,b)=8192, fp32 vector FMA)
//          then per-neuron sequential scan over t (leaky IF + reset).
// Layouts: intermediates kept as X[(t*64+b)*O + o] so scans are fully coalesced
// (index = t*BO + n) and GEMM2/3 read standard row-major [M,K].
// ws: two 32 MB ping-pong buffers; all bytes written before read (poison-safe).

#define T_DIM 128
#define B_DIM 64
#define TILE  128
#define KC    16
#define LDSP  132   // padded LDS row stride (floats); 132*4 B is 16B-aligned per row

template<bool A_SPIKE>
__global__ __launch_bounds__(256)
void gemm_tile(const float* __restrict__ A, const float* __restrict__ W,
               float* __restrict__ Z, int K, int O) {
  // A_SPIKE: A is spike[b][k][T] (b = blockIdx.y, tile row r == t)
  // else:    A is X[m][k] row-major (m-tile = blockIdx.y)
  __shared__ float As[KC][LDSP];
  __shared__ float Bs[KC][LDSP];
  const int tid = threadIdx.x;
  const int tx = tid & 15;   // -> o (8 outputs)
  const int ty = tid >> 4;   // -> m (8 rows)
  const int o0 = blockIdx.x * TILE;
  const int bm = blockIdx.y;

  float acc[8][8];
#pragma unroll
  for (int i = 0; i < 8; ++i)
#pragma unroll
    for (int j = 0; j < 8; ++j) acc[i][j] = 0.0f;

  const int s_kk = tid >> 4;          // A_SPIKE staging: k within chunk
  const int s_r  = (tid & 15) << 3;   // A_SPIKE staging: t offset
  const int l_r  = tid >> 1;          // linear staging: row 0..127
  const int l_k  = (tid & 1) << 3;    // linear staging: k half (0 or 8)

  for (int kc = 0; kc < K; kc += KC) {
    if (A_SPIKE) {
      // As[kk][t] <- spike[bm][kc+kk][t] ; rows contiguous in t
      const float* src = A + ((size_t)bm * K + kc + s_kk) * T_DIM + s_r;
      float4 v0 = *(const float4*)src;
      float4 v1 = *(const float4*)(src + 4);
      *(float4*)&As[s_kk][s_r]     = v0;
      *(float4*)&As[s_kk][s_r + 4] = v1;
    } else {
      // As[kk][r] <- A[(m0+r)][kc+kk] ; transpose into k-major LDS
      const float* src = A + (size_t)(bm * TILE + l_r) * K + kc + l_k;
      float4 v0 = *(const float4*)src;
      float4 v1 = *(const float4*)(src + 4);
      As[l_k + 0][l_r] = v0.x; As[l_k + 1][l_r] = v0.y;
      As[l_k + 2][l_r] = v0.z; As[l_k + 3][l_r] = v0.w;
      As[l_k + 4][l_r] = v1.x; As[l_k + 5][l_r] = v1.y;
      As[l_k + 6][l_r] = v1.z; As[l_k + 7][l_r] = v1.w;
    }
    {
      // Bs[kk][ol] <- W[(o0+ol)][kc+kk]
      const float* src = W + (size_t)(o0 + l_r) * K + kc + l_k;
      float4 v0 = *(const float4*)src;
      float4 v1 = *(const float4*)(src + 4);
      Bs[l_k + 0][l_r] = v0.x; Bs[l_k + 1][l_r] = v0.y;
      Bs[l_k + 2][l_r] = v0.z; Bs[l_k + 3][l_r] = v0.w;
      Bs[l_k + 4][l_r] = v1.x; Bs[l_k + 5][l_r] = v1.y;
      Bs[l_k + 6][l_r] = v1.z; Bs[l_k + 7][l_r] = v1.w;
    }
    __syncthreads();
#pragma unroll
    for (int kk = 0; kk < KC; ++kk) {
      float4 a0 = *(const float4*)&As[kk][ty << 3];
      float4 a1 = *(const float4*)&As[kk][(ty << 3) + 4];
      float4 b0 = *(const float4*)&Bs[kk][tx << 3];
      float4 b1 = *(const float4*)&Bs[kk][(tx << 3) + 4];
      float a[8] = {a0.x, a0.y, a0.z, a0.w, a1.x, a1.y, a1.z, a1.w};
      float b[8] = {b0.x, b0.y, b0.z, b0.w, b1.x, b1.y, b1.z, b1.w};
#pragma unroll
      for (int i = 0; i < 8; ++i)
#pragma unroll
        for (int j = 0; j < 8; ++j)
          acc[i][j] = fmaf(a[i], b[j], acc[i][j]);
    }
    __syncthreads();
  }

#pragma unroll
  for (int i = 0; i < 8; ++i) {
    int r = (ty << 3) + i;
    size_t m = A_SPIKE ? ((size_t)r * B_DIM + bm) : ((size_t)bm * TILE + r);
    float* dst = Z + m * (size_t)O + o0 + (tx << 3);
    *(float4*)dst       = make_float4(acc[i][0], acc[i][1], acc[i][2], acc[i][3]);
    *(float4*)(dst + 4) = make_float4(acc[i][4], acc[i][5], acc[i][6], acc[i][7]);
  }
}

// Leaky-IF scan over t for B*O neurons. Z and S indexed [t*BO + n] -> coalesced.
// Decay constants: float(1.0-0.3)=0.7f, float(1.0-0.8)=0.2f (matches numpy/jax
// weak-typed python-scalar promotion). fp contract OFF to mirror numpy's
// separate mul/add roundings.
__global__ __launch_bounds__(256)
void scan_mid(const float* __restrict__ Z, float* __restrict__ S, int BO) {
#pragma clang fp contract(off)
  const int n = blockIdx.x * 256 + threadIdx.x;
  float cur = 0.0f, vol = 0.0f;
  for (int t = 0; t < T_DIM; ++t) {
    float z = Z[(size_t)t * BO + n];
    cur = cur * 0.7f;
    cur = cur + z;
    vol = vol * 0.2f;
    vol = vol + cur;
    float v = vol - 1.0f;
    float s = (v >= 0.0f) ? 1.0f : 0.0f;
    vol = vol * (1.0f - s);
    S[(size_t)t * BO + n] = s;
  }
}

// Layer-3 GEMM: one wave per m-row, 2 output dots of length 1024.
__global__ __launch_bounds__(256)
void gemm3(const float* __restrict__ X, const float* __restrict__ W3,
           float* __restrict__ Z3) {
  const int wave = threadIdx.x >> 6;
  const int lane = threadIdx.x & 63;
  const int m = blockIdx.x * 4 + wave;
  const float* x = X + (size_t)m * 1024;
  float s0 = 0.0f, s1 = 0.0f;
#pragma unroll
  for (int j = 0; j < 16; ++j) {
    int i = lane + j * 64;
    float xv = x[i];
    s0 = fmaf(xv, W3[i], s0);
    s1 = fmaf(xv, W3[1024 + i], s1);
  }
#pragma unroll
  for (int off = 32; off > 0; off >>= 1) {
    s0 += __shfl_down(s0, off);
    s1 += __shfl_down(s1, off);
  }
  if (lane == 0) {
    Z3[(size_t)m * 2]     = s0;
    Z3[(size_t)m * 2 + 1] = s1;
  }
}

// Final scan: 128 neurons (b,o). Z3 index (t*64+b)*2+o = t*128+n. Output [B,2,T].
__global__ void scan3(const float* __restrict__ Z, float* __restrict__ out) {
#pragma clang fp contract(off)
  const int n = threadIdx.x;  // 0..127, n = b*2 + o
  float cur = 0.0f, vol = 0.0f;
  for (int t = 0; t < T_DIM; ++t) {
    float z = Z[t * 128 + n];
    cur = cur * 0.7f;
    cur = cur + z;
    vol = vol * 0.2f;
    vol = vol + cur;
    float v = vol - 1.0f;
    float s = (v >= 0.0f) ? 1.0f : 0.0f;
    vol = vol * (1.0f - s);
    out[n * 128 + t] = s;
  }
}

extern "C" void kernel_launch(void* const* d_in, const int* in_sizes, int n_in,
                              void* d_out, int out_size, void* d_ws, size_t ws_size,
                              hipStream_t stream) {
  const float* spike = (const float*)d_in[0];  // [64, 2048, 128]
  const float* W1    = (const float*)d_in[1];  // [1024, 2048]
  const float* W2    = (const float*)d_in[2];  // [1024, 1024]
  const float* W3    = (const float*)d_in[3];  // [2, 1024]
  float* out = (float*)d_out;                  // [64, 2, 128]

  float* ws0 = (float*)d_ws;                   // 32 MB
  float* ws1 = ws0 + (size_t)8192 * 1024;      // 32 MB

  // L1: Z1 = spike x W1^T  -> ws0   (M=8192 as (t*64+b), O=1024, K=2048)
  gemm_tile<true><<<dim3(8, 64), 256, 0, stream>>>(spike, W1, ws0, 2048, 1024);
  // scan1: ws0 -> spikes X2 in ws1
  scan_mid<<<256, 256, 0, stream>>>(ws0, ws1, 65536);
  // L2: Z2 = X2 x W2^T -> ws0
  gemm_tile<false><<<dim3(8, 64), 256, 0, stream>>>(ws1, W2, ws0, 1024, 1024);
  // scan2: ws0 -> spikes X3 in ws1
  scan_mid<<<256, 256, 0, stream>>>(ws0, ws1, 65536);
  // L3: Z3 = X3 x W3^T -> ws0 (64 KB used)
  gemm3<<<2048, 256, 0, stream>>>(ws1, W3, ws0);
  // scan3: ws0 -> out
  scan3<<<1, 128, 0, stream>>>(ws0, out);
}

// Round 3
// 289.186 us; speedup vs baseline: 2.4496x; 2.4496x over previous
//
#include <hip/hip_runtime.h>

// SLAYER 3-layer CUBA SNN, MFMA version.
// Spikes are exactly 0/1 -> exact in bf16. Weights split W = hi + lo where
// hi = bf16_rne(W), lo = bf16_rne(W - hi); Z = A*hi + A*lo with fp32-accum
// bf16 MFMA reproduces the fp32 GEMM to ~2^-18 relative — far inside the
// spike-flip margin (fp32 version passed with absmax 0.0).
// GEMM: 128x128 tile, 16x16x32 bf16 MFMA, global_load_lds width=16.
// Layout: m = t*64+b so scans are coalesced (index t*BO+n), GEMMs row-major.

typedef unsigned short ushort_t;
typedef unsigned int uint_t;
typedef __bf16 bf16x8 __attribute__((ext_vector_type(8)));
typedef float f32x4 __attribute__((ext_vector_type(4)));

#define T_DIM 128
#define B_DIM 64

__device__ __forceinline__ void glds16(const ushort_t* g, ushort_t* l) {
  __builtin_amdgcn_global_load_lds(
      (const __attribute__((address_space(1))) uint_t*)g,
      (__attribute__((address_space(3))) uint_t*)l, 16, 0, 0);
}

// round-to-nearest-even fp32 -> bf16 (bit pattern), finite inputs
__device__ __forceinline__ ushort_t f32_to_bf16_rne(float f) {
  uint_t u = __float_as_uint(f);
  u += 0x7FFFu + ((u >> 16) & 1u);
  return (ushort_t)(u >> 16);
}

// ---------------- W split: hi/lo bf16 planes ----------------
__global__ __launch_bounds__(256) void split_w(const float* __restrict__ W,
                                               ushort_t* __restrict__ hi,
                                               ushort_t* __restrict__ lo, int n) {
  int idx = blockIdx.x * 256 + threadIdx.x;
  if (idx >= n) return;
  float w = W[idx];
  ushort_t h = f32_to_bf16_rne(w);
  float hf = __uint_as_float(((uint_t)h) << 16);
  hi[idx] = h;
  lo[idx] = f32_to_bf16_rne(w - hf);
}

// ---------------- spike [b][i][t] fp32 -> A1 [t*64+b][i] bf16 ----------------
__global__ __launch_bounds__(256) void transpose_spike(const float* __restrict__ spike,
                                                       ushort_t* __restrict__ A1) {
  __shared__ uint_t lds[32 * 129];
  const int tid = threadIdx.x;
  const int b = blockIdx.y;
  const int i0 = blockIdx.x * 32;
#pragma unroll
  for (int it = 0; it < 16; ++it) {
    int p = it * 256 + tid;
    int i = p >> 7, t = p & 127;
    float v = spike[((size_t)b * 2048 + i0 + i) * T_DIM + t];
    lds[i * 129 + t] = (v != 0.0f) ? 0x3F80u : 0u;  // bf16 bits of 1.0 / 0.0
  }
  __syncthreads();
  uint_t* A1u = (uint_t*)A1;
#pragma unroll
  for (int it = 0; it < 8; ++it) {
    int p = it * 256 + tid;
    int t = p >> 4, iu = p & 15;
    uint_t u = lds[(2 * iu) * 129 + t] | (lds[(2 * iu + 1) * 129 + t] << 16);
    A1u[((size_t)(t * 64 + b) * 2048 + i0) / 2 + iu] = u;
  }
}

// ---------------- MFMA GEMM: Z[m][o] = sum_k A[m][k]*(Whi[o][k]+Wlo[o][k]) ---
__global__ __launch_bounds__(256)
void gemm_mfma(const ushort_t* __restrict__ A, const ushort_t* __restrict__ Bhi,
               const ushort_t* __restrict__ Blo, float* __restrict__ Z,
               int K, int O) {
  __shared__ ushort_t As[128 * 32];
  __shared__ ushort_t Bh[128 * 32];
  __shared__ ushort_t Bl[128 * 32];
  const int tid = threadIdx.x;
  const int wave = tid >> 6;
  const int lane = tid & 63;
  const int m0 = blockIdx.y * 128;
  const int o0 = blockIdx.x * 128;
  const int wm = (wave >> 1) * 64;
  const int wn = (wave & 1) * 64;
  const int fr = lane & 15;  // fragment row/col
  const int q = lane >> 4;   // quad

  f32x4 acc[4][4];
#pragma unroll
  for (int i = 0; i < 4; ++i)
#pragma unroll
    for (int j = 0; j < 4; ++j) acc[i][j] = (f32x4){0.f, 0.f, 0.f, 0.f};

  // staging: wave handles row-chunks c0=2*wave, c0+1 (16 rows each, 32 k)
  const int arow = lane >> 2;        // row within chunk
  const int akin = (lane & 3) * 8;   // k offset within 32
  const int c0 = 2 * wave;
  const size_t ga0 = (size_t)(m0 + c0 * 16 + arow) * K + akin;
  const size_t ga1 = ga0 + (size_t)16 * K;
  const size_t gb0 = (size_t)(o0 + c0 * 16 + arow) * K + akin;
  const size_t gb1 = gb0 + (size_t)16 * K;
  ushort_t* lA0 = As + c0 * 16 * 32;
  ushort_t* lA1 = As + (c0 + 1) * 16 * 32;
  ushort_t* lBh0 = Bh + c0 * 16 * 32;
  ushort_t* lBh1 = Bh + (c0 + 1) * 16 * 32;
  ushort_t* lBl0 = Bl + c0 * 16 * 32;
  ushort_t* lBl1 = Bl + (c0 + 1) * 16 * 32;

  for (int kc = 0; kc < K; kc += 32) {
    glds16(A + ga0 + kc, lA0);
    glds16(A + ga1 + kc, lA1);
    glds16(Bhi + gb0 + kc, lBh0);
    glds16(Bhi + gb1 + kc, lBh1);
    glds16(Blo + gb0 + kc, lBl0);
    glds16(Blo + gb1 + kc, lBl1);
    __syncthreads();

    bf16x8 af[4], bh[4], bl[4];
#pragma unroll
    for (int i = 0; i < 4; ++i)
      af[i] = *(const bf16x8*)(As + (wm + i * 16 + fr) * 32 + q * 8);
#pragma unroll
    for (int j = 0; j < 4; ++j) {
      bh[j] = *(const bf16x8*)(Bh + (wn + j * 16 + fr) * 32 + q * 8);
      bl[j] = *(const bf16x8*)(Bl + (wn + j * 16 + fr) * 32 + q * 8);
    }
#pragma unroll
    for (int i = 0; i < 4; ++i)
#pragma unroll
      for (int j = 0; j < 4; ++j) {
        acc[i][j] = __builtin_amdgcn_mfma_f32_16x16x32_bf16(af[i], bh[j], acc[i][j], 0, 0, 0);
        acc[i][j] = __builtin_amdgcn_mfma_f32_16x16x32_bf16(af[i], bl[j], acc[i][j], 0, 0, 0);
      }
    __syncthreads();
  }

  // epilogue: C/D layout col=lane&15, row=q*4+reg
#pragma unroll
  for (int i = 0; i < 4; ++i)
#pragma unroll
    for (int j = 0; j < 4; ++j) {
      float* dst = Z + (size_t)(m0 + wm + i * 16 + q * 4) * O + o0 + wn + j * 16 + fr;
#pragma unroll
      for (int rr = 0; rr < 4; ++rr) dst[(size_t)rr * O] = acc[i][j][rr];
    }
}

// ---------------- leaky-IF scan, emits bf16 spikes ----------------
__global__ __launch_bounds__(256) void scan_bf(const float* __restrict__ Z,
                                               ushort_t* __restrict__ S, int BO) {
#pragma clang fp contract(off)
  const int n = blockIdx.x * 256 + threadIdx.x;
  float cur = 0.0f, vol = 0.0f;
  for (int t = 0; t < T_DIM; ++t) {
    float z = Z[(size_t)t * BO + n];
    cur = cur * 0.7f;
    cur = cur + z;
    vol = vol * 0.2f;
    vol = vol + cur;
    float v = vol - 1.0f;
    float s = (v >= 0.0f) ? 1.0f : 0.0f;
    vol = vol * (1.0f - s);
    S[(size_t)t * BO + n] = (v >= 0.0f) ? 0x3F80u : 0u;
  }
}

// ---------------- layer-3 GEMM (O=2), bf16 spikes in, fp32 math -------------
__global__ __launch_bounds__(256) void gemm3(const ushort_t* __restrict__ X,
                                             const float* __restrict__ W3,
                                             float* __restrict__ Z3) {
  const int wave = threadIdx.x >> 6;
  const int lane = threadIdx.x & 63;
  const int m = blockIdx.x * 4 + wave;
  const ushort_t* x = X + (size_t)m * 1024;
  float s0 = 0.0f, s1 = 0.0f;
#pragma unroll
  for (int j = 0; j < 16; ++j) {
    int i = lane + j * 64;
    float xv = __uint_as_float(((uint_t)x[i]) << 16);
    s0 = fmaf(xv, W3[i], s0);
    s1 = fmaf(xv, W3[1024 + i], s1);
  }
#pragma unroll
  for (int off = 32; off > 0; off >>= 1) {
    s0 += __shfl_down(s0, off);
    s1 += __shfl_down(s1, off);
  }
  if (lane == 0) {
    Z3[(size_t)m * 2] = s0;
    Z3[(size_t)m * 2 + 1] = s1;
  }
}

__global__ void scan3(const float* __restrict__ Z, float* __restrict__ out) {
#pragma clang fp contract(off)
  const int n = threadIdx.x;  // n = b*2 + o
  float cur = 0.0f, vol = 0.0f;
  for (int t = 0; t < T_DIM; ++t) {
    float z = Z[t * 128 + n];
    cur = cur * 0.7f;
    cur = cur + z;
    vol = vol * 0.2f;
    vol = vol + cur;
    float v = vol - 1.0f;
    float s = (v >= 0.0f) ? 1.0f : 0.0f;
    vol = vol * (1.0f - s);
    out[n * 128 + t] = s;
  }
}

extern "C" void kernel_launch(void* const* d_in, const int* in_sizes, int n_in,
                              void* d_out, int out_size, void* d_ws, size_t ws_size,
                              hipStream_t stream) {
  const float* spike = (const float*)d_in[0];  // [64, 2048, 128]
  const float* W1 = (const float*)d_in[1];     // [1024, 2048]
  const float* W2 = (const float*)d_in[2];     // [1024, 1024]
  const float* W3 = (const float*)d_in[3];     // [2, 1024]
  float* out = (float*)d_out;                  // [64, 2, 128]

  char* ws = (char*)d_ws;
  // R0 (32 MB): A1 [8192][2048] bf16; later A2 = R0[0..16MB), A3 = R0[16..32MB)
  ushort_t* A1 = (ushort_t*)ws;
  ushort_t* A2 = (ushort_t*)ws;
  ushort_t* A3 = (ushort_t*)(ws + (size_t)16 * 1024 * 1024);
  float* Zbuf = (float*)(ws + (size_t)32 * 1024 * 1024);        // 32 MB fp32
  ushort_t* W1hi = (ushort_t*)(ws + (size_t)64 * 1024 * 1024);  // 4 MB
  ushort_t* W1lo = (ushort_t*)(ws + (size_t)68 * 1024 * 1024);  // 4 MB
  ushort_t* W2hi = (ushort_t*)(ws + (size_t)72 * 1024 * 1024);  // 2 MB
  ushort_t* W2lo = (ushort_t*)(ws + (size_t)74 * 1024 * 1024);  // 2 MB
  float* Z3 = (float*)(ws + (size_t)76 * 1024 * 1024);          // 64 KB

  split_w<<<8192, 256, 0, stream>>>(W1, W1hi, W1lo, 1024 * 2048);
  split_w<<<4096, 256, 0, stream>>>(W2, W2hi, W2lo, 1024 * 1024);
  transpose_spike<<<dim3(64, 64), 256, 0, stream>>>(spike, A1);

  // L1: M=8192, K=2048, O=1024
  gemm_mfma<<<dim3(8, 64), 256, 0, stream>>>(A1, W1hi, W1lo, Zbuf, 2048, 1024);
  scan_bf<<<256, 256, 0, stream>>>(Zbuf, A2, 65536);
  // L2: M=8192, K=1024, O=1024
  gemm_mfma<<<dim3(8, 64), 256, 0, stream>>>(A2, W2hi, W2lo, Zbuf, 1024, 1024);
  scan_bf<<<256, 256, 0, stream>>>(Zbuf, A3, 65536);
  // L3
  gemm3<<<2048, 256, 0, stream>>>(A3, W3, Z3);
  scan3<<<1, 128, 0, stream>>>(Z3, out);
}

// Round 4
// 275.837 us; speedup vs baseline: 2.5681x; 1.0484x over previous
//
#include <hip/hip_runtime.h>

// SLAYER 3-layer CUBA SNN — MFMA GEMM with FUSED leaky-IF scan epilogue.
// Row layout m = b*128 + t: one 128-row m-tile = all T=128 timesteps of one
// batch element, so each GEMM block holds the full Z[t][o] history for its
// o-columns in registers at K-loop end -> stage to LDS, scan over t in-block,
// emit bf16 spikes directly (no Z round-trip to HBM, no separate scan kernels).
// Weights: W = hi + lo bf16 planes (exact-in-bf16 spikes make A*hi + A*lo
// reproduce fp32 GEMM to ~2^-18 rel; R3 passed absmax 0.0 with this).
// o-tile 64 -> grid 16x64 = 1024 blocks = 4 blocks/CU (vs 2 in R3).

typedef unsigned short ushort_t;
typedef unsigned int uint_t;
typedef __bf16 bf16x8 __attribute__((ext_vector_type(8)));
typedef float f32x4 __attribute__((ext_vector_type(4)));

#define O_TOT 1024

__device__ __forceinline__ void glds16(const ushort_t* g, ushort_t* l) {
  __builtin_amdgcn_global_load_lds(
      (const __attribute__((address_space(1))) uint_t*)g,
      (__attribute__((address_space(3))) uint_t*)l, 16, 0, 0);
}

// round-to-nearest-even fp32 -> bf16 bits (finite inputs)
__device__ __forceinline__ ushort_t f32_to_bf16_rne(float f) {
  uint_t u = __float_as_uint(f);
  u += 0x7FFFu + ((u >> 16) & 1u);
  return (ushort_t)(u >> 16);
}

// ---------------- W1+W2 split into hi/lo bf16 planes (one launch) -----------
__global__ __launch_bounds__(256) void split_w(const float* __restrict__ W1,
                                               const float* __restrict__ W2,
                                               ushort_t* __restrict__ h1,
                                               ushort_t* __restrict__ l1,
                                               ushort_t* __restrict__ h2,
                                               ushort_t* __restrict__ l2) {
  int idx = blockIdx.x * 256 + threadIdx.x;
  const int N1 = 1024 * 2048;
  if (idx < N1) {
    float w = W1[idx];
    ushort_t h = f32_to_bf16_rne(w);
    h1[idx] = h;
    l1[idx] = f32_to_bf16_rne(w - __uint_as_float(((uint_t)h) << 16));
  } else {
    int k = idx - N1;
    float w = W2[k];
    ushort_t h = f32_to_bf16_rne(w);
    h2[k] = h;
    l2[k] = f32_to_bf16_rne(w - __uint_as_float(((uint_t)h) << 16));
  }
}

// ---------------- spike [b][i][t] fp32 -> A1 [b*128+t][i] bf16 --------------
__global__ __launch_bounds__(256) void transpose_spike(const float* __restrict__ spike,
                                                       ushort_t* __restrict__ A1) {
  __shared__ uint_t lds[32 * 129];
  const int tid = threadIdx.x;
  const int b = blockIdx.y;
  const int i0 = blockIdx.x * 32;
#pragma unroll
  for (int it = 0; it < 16; ++it) {
    int p = it * 256 + tid;
    int i = p >> 7, t = p & 127;
    float v = spike[((size_t)b * 2048 + i0 + i) * 128 + t];
    lds[i * 129 + t] = (v != 0.0f) ? 0x3F80u : 0u;  // bf16 bits of 1.0 / 0.0
  }
  __syncthreads();
  uint_t* A1u = (uint_t*)A1;
#pragma unroll
  for (int it = 0; it < 8; ++it) {
    int p = it * 256 + tid;
    int t = p >> 4, iu = p & 15;
    uint_t u = lds[(2 * iu) * 129 + t] | (lds[(2 * iu + 1) * 129 + t] << 16);
    A1u[((size_t)(b * 128 + t) * 2048 + i0) / 2 + iu] = u;
  }
}

// ------- fused GEMM (128m x 64o tile, hi/lo bf16 MFMA) + leaky-IF scan ------
// Z[m][o] = sum_k A[m][k]*(Whi[o][k]+Wlo[o][k]); then scan over t per o-col,
// spikes (bf16 bits) -> S[(b*128+t)*1024 + o].
__global__ __launch_bounds__(256, 4)
void gemm_scan(const ushort_t* __restrict__ A, const ushort_t* __restrict__ Bhi,
               const ushort_t* __restrict__ Blo, ushort_t* __restrict__ S,
               int K) {
  __shared__ float smemf[128 * 65];  // 33.3 KB: staging (16 KB) U Z-tile
  ushort_t* As = (ushort_t*)smemf;   // 128 x 32
  ushort_t* Bh = As + 128 * 32;      // 64 x 32
  ushort_t* Bl = Bh + 64 * 32;       // 64 x 32
  float* Zt = smemf;                 // [128 t][65] padded

  const int tid = threadIdx.x;
  const int wave = tid >> 6, lane = tid & 63;
  const int b = blockIdx.y;
  const int m0 = b * 128;
  const int o0 = blockIdx.x * 64;
  const int qm = wave >> 1, qn = wave & 1;
  const int fr = lane & 15, q = lane >> 4;

  f32x4 acc[4][2];
#pragma unroll
  for (int i = 0; i < 4; ++i)
#pragma unroll
    for (int j = 0; j < 2; ++j) acc[i][j] = (f32x4){0.f, 0.f, 0.f, 0.f};

  // staging: wave stages A rows [32w,32w+32) (2 chunks) + B rows [16w,16w+16)
  const int srow = lane >> 2;
  const int skin = (lane & 3) * 8;
  const size_t ga0 = (size_t)(m0 + wave * 32 + srow) * K + skin;
  const size_t ga1 = ga0 + (size_t)16 * K;
  const size_t gb = (size_t)(o0 + wave * 16 + srow) * K + skin;
  ushort_t* lA0 = As + (wave * 32) * 32;
  ushort_t* lA1 = As + (wave * 32 + 16) * 32;
  ushort_t* lBh = Bh + (wave * 16) * 32;
  ushort_t* lBl = Bl + (wave * 16) * 32;

  for (int kc = 0; kc < K; kc += 32) {
    glds16(A + ga0 + kc, lA0);
    glds16(A + ga1 + kc, lA1);
    glds16(Bhi + gb + kc, lBh);
    glds16(Blo + gb + kc, lBl);
    __syncthreads();

    bf16x8 af[4], bh[2], bl[2];
#pragma unroll
    for (int i = 0; i < 4; ++i)
      af[i] = *(const bf16x8*)(As + (qm * 64 + i * 16 + fr) * 32 + q * 8);
#pragma unroll
    for (int j = 0; j < 2; ++j) {
      bh[j] = *(const bf16x8*)(Bh + (qn * 32 + j * 16 + fr) * 32 + q * 8);
      bl[j] = *(const bf16x8*)(Bl + (qn * 32 + j * 16 + fr) * 32 + q * 8);
    }
#pragma unroll
    for (int i = 0; i < 4; ++i)
#pragma unroll
      for (int j = 0; j < 2; ++j) {
        acc[i][j] = __builtin_amdgcn_mfma_f32_16x16x32_bf16(af[i], bh[j], acc[i][j], 0, 0, 0);
        acc[i][j] = __builtin_amdgcn_mfma_f32_16x16x32_bf16(af[i], bl[j], acc[i][j], 0, 0, 0);
      }
    __syncthreads();
  }

  // acc -> LDS Z-tile: t = qm*64+i*16+q*4+rr, o-local = qn*32+j*16+fr
#pragma unroll
  for (int i = 0; i < 4; ++i)
#pragma unroll
    for (int j = 0; j < 2; ++j)
#pragma unroll
      for (int rr = 0; rr < 4; ++rr)
        Zt[(qm * 64 + i * 16 + q * 4 + rr) * 65 + qn * 32 + j * 16 + fr] = acc[i][j][rr];
  __syncthreads();

  // fused leaky-IF scan: thread tid<64 owns o-column (o0+tid)
  if (tid < 64) {
#pragma clang fp contract(off)
    float cur = 0.0f, vol = 0.0f;
    const int o = o0 + tid;
    for (int t = 0; t < 128; ++t) {
      float z = Zt[t * 65 + tid];
      cur = cur * 0.7f;
      cur = cur + z;
      vol = vol * 0.2f;
      vol = vol + cur;
      float v = vol - 1.0f;
      float s = (v >= 0.0f) ? 1.0f : 0.0f;
      vol = vol * (1.0f - s);
      S[(size_t)(m0 + t) * O_TOT + o] = (v >= 0.0f) ? 0x3F80u : 0u;
    }
  }
}

// ---------- layer 3 fused: per-b dense (O=2, fp32) + scan + output ----------
__global__ __launch_bounds__(256) void gemm3_scan(const ushort_t* __restrict__ X,
                                                  const float* __restrict__ W3,
                                                  float* __restrict__ out) {
  __shared__ float w3s[2048];
  __shared__ float z3[256];  // [t*2 + o]
  __shared__ float sp[256];  // [o*128 + t]
  const int tid = threadIdx.x;
  const int b = blockIdx.x;
  for (int i = tid; i < 2048; i += 256) w3s[i] = W3[i];
  __syncthreads();
  const int wave = tid >> 6, lane = tid & 63;
  for (int tt = 0; tt < 32; ++tt) {
    int t = wave * 32 + tt;
    const uint_t* row = (const uint_t*)(X + (size_t)(b * 128 + t) * 1024) + lane * 8;
    float s0 = 0.0f, s1 = 0.0f;
#pragma unroll
    for (int jw = 0; jw < 8; ++jw) {
      uint_t u = row[jw];
      float x0 = __uint_as_float(u << 16);
      float x1 = __uint_as_float(u & 0xFFFF0000u);
      int i0 = lane * 16 + jw * 2;
      s0 = fmaf(x0, w3s[i0], s0);
      s1 = fmaf(x0, w3s[1024 + i0], s1);
      s0 = fmaf(x1, w3s[i0 + 1], s0);
      s1 = fmaf(x1, w3s[1024 + i0 + 1], s1);
    }
#pragma unroll
    for (int off = 32; off > 0; off >>= 1) {
      s0 += __shfl_down(s0, off);
      s1 += __shfl_down(s1, off);
    }
    if (lane == 0) {
      z3[t * 2] = s0;
      z3[t * 2 + 1] = s1;
    }
  }
  __syncthreads();
  if (tid < 2) {
#pragma clang fp contract(off)
    float cur = 0.0f, vol = 0.0f;
    for (int t = 0; t < 128; ++t) {
      float z = z3[t * 2 + tid];
      cur = cur * 0.7f;
      cur = cur + z;
      vol = vol * 0.2f;
      vol = vol + cur;
      float v = vol - 1.0f;
      float s = (v >= 0.0f) ? 1.0f : 0.0f;
      vol = vol * (1.0f - s);
      sp[tid * 128 + t] = s;
    }
  }
  __syncthreads();
  out[b * 256 + tid] = sp[tid];
}

extern "C" void kernel_launch(void* const* d_in, const int* in_sizes, int n_in,
                              void* d_out, int out_size, void* d_ws, size_t ws_size,
                              hipStream_t stream) {
  const float* spike = (const float*)d_in[0];  // [64, 2048, 128]
  const float* W1 = (const float*)d_in[1];     // [1024, 2048]
  const float* W2 = (const float*)d_in[2];     // [1024, 1024]
  const float* W3 = (const float*)d_in[3];     // [2, 1024]
  float* out = (float*)d_out;                  // [64, 2, 128]

  char* ws = (char*)d_ws;
  ushort_t* A1 = (ushort_t*)ws;                                 // 32 MB
  ushort_t* S2 = (ushort_t*)(ws + (size_t)32 * 1024 * 1024);    // 16 MB
  ushort_t* S3 = (ushort_t*)(ws + (size_t)48 * 1024 * 1024);    // 16 MB
  ushort_t* W1hi = (ushort_t*)(ws + (size_t)64 * 1024 * 1024);  // 4 MB
  ushort_t* W1lo = (ushort_t*)(ws + (size_t)68 * 1024 * 1024);  // 4 MB
  ushort_t* W2hi = (ushort_t*)(ws + (size_t)72 * 1024 * 1024);  // 2 MB
  ushort_t* W2lo = (ushort_t*)(ws + (size_t)74 * 1024 * 1024);  // 2 MB

  split_w<<<12288, 256, 0, stream>>>(W1, W2, W1hi, W1lo, W2hi, W2lo);
  transpose_spike<<<dim3(64, 64), 256, 0, stream>>>(spike, A1);
  // L1: M=8192 (b*128+t), K=2048, O=1024
  gemm_scan<<<dim3(16, 64), 256, 0, stream>>>(A1, W1hi, W1lo, S2, 2048);
  // L2: K=1024
  gemm_scan<<<dim3(16, 64), 256, 0, stream>>>(S2, W2hi, W2lo, S3, 1024);
  // L3 + final scan + output
  gemm3_scan<<<64, 256, 0, stream>>>(S3, W3, out);
}

// Round 5
// 241.654 us; speedup vs baseline: 2.9314x; 1.1415x over previous
//
#include <hip/hip_runtime.h>

// SLAYER 3-layer CUBA SNN — fused MFMA GEMM + leaky-IF scan.
// R5: K-chunk 64 (half the barriers of R4), XOR-swizzled LDS slots for
// conflict-free ds_read_b128 frag reads, o-tile 64, 4 blocks/CU.
// Weights: W = hi + lo bf16 planes; spikes exact in bf16 -> A*hi + A*lo
// reproduces fp32 GEMM to ~2^-18 rel (R3/R4 passed absmax 0.0).
// Layout m = b*128 + t: block holds full Z[t][o] history -> in-LDS scan.

typedef unsigned short ushort_t;
typedef unsigned int uint_t;
typedef __bf16 bf16x8 __attribute__((ext_vector_type(8)));
typedef float f32x4 __attribute__((ext_vector_type(4)));

#define O_TOT 1024

__device__ __forceinline__ void glds16(const ushort_t* g, ushort_t* l) {
  __builtin_amdgcn_global_load_lds(
      (const __attribute__((address_space(1))) uint_t*)g,
      (__attribute__((address_space(3))) uint_t*)l, 16, 0, 0);
}

__device__ __forceinline__ ushort_t f32_to_bf16_rne(float f) {
  uint_t u = __float_as_uint(f);
  u += 0x7FFFu + ((u >> 16) & 1u);
  return (ushort_t)(u >> 16);
}

// ---------------- W1+W2 split into hi/lo bf16 planes (one launch) -----------
__global__ __launch_bounds__(256) void split_w(const float* __restrict__ W1,
                                               const float* __restrict__ W2,
                                               ushort_t* __restrict__ h1,
                                               ushort_t* __restrict__ l1,
                                               ushort_t* __restrict__ h2,
                                               ushort_t* __restrict__ l2) {
  int idx = blockIdx.x * 256 + threadIdx.x;
  const int N1 = 1024 * 2048;
  if (idx < N1) {
    float w = W1[idx];
    ushort_t h = f32_to_bf16_rne(w);
    h1[idx] = h;
    l1[idx] = f32_to_bf16_rne(w - __uint_as_float(((uint_t)h) << 16));
  } else {
    int k = idx - N1;
    float w = W2[k];
    ushort_t h = f32_to_bf16_rne(w);
    h2[k] = h;
    l2[k] = f32_to_bf16_rne(w - __uint_as_float(((uint_t)h) << 16));
  }
}

// ---------------- spike [b][i][t] fp32 -> A1 [b*128+t][i] bf16 --------------
__global__ __launch_bounds__(256) void transpose_spike(const float* __restrict__ spike,
                                                       ushort_t* __restrict__ A1) {
  __shared__ ushort_t lds[32 * 130];
  const int tid = threadIdx.x;
  const int b = blockIdx.y;
  const int i0 = blockIdx.x * 32;
#pragma unroll
  for (int it = 0; it < 4; ++it) {
    int p = it * 256 + tid;
    int i = p >> 5, tg = (p & 31) * 4;
    float4 v = *(const float4*)(spike + ((size_t)b * 2048 + i0 + i) * 128 + tg);
    lds[i * 130 + tg + 0] = (v.x != 0.0f) ? 0x3F80u : 0u;
    lds[i * 130 + tg + 1] = (v.y != 0.0f) ? 0x3F80u : 0u;
    lds[i * 130 + tg + 2] = (v.z != 0.0f) ? 0x3F80u : 0u;
    lds[i * 130 + tg + 3] = (v.w != 0.0f) ? 0x3F80u : 0u;
  }
  __syncthreads();
  uint_t* A1u = (uint_t*)A1;
#pragma unroll
  for (int it = 0; it < 8; ++it) {
    int p = it * 256 + tid;
    int t = p >> 4, iu = p & 15;
    uint_t u = (uint_t)lds[(2 * iu) * 130 + t] | ((uint_t)lds[(2 * iu + 1) * 130 + t] << 16);
    A1u[((size_t)(b * 128 + t) * 2048 + i0) / 2 + iu] = u;
  }
}

// ------- fused GEMM (128m x 64o tile, K-chunk 64, hi/lo bf16) + scan --------
// LDS slot swizzle: tile row has 8 16B-slots (64 bf16); slot(row,u) =
// row*8 + (u ^ (row&7)) -> frag ds_read_b128 covers all 32 banks per 8 lanes.
__global__ __launch_bounds__(256, 4)
void gemm_scan(const ushort_t* __restrict__ A, const ushort_t* __restrict__ Bhi,
               const ushort_t* __restrict__ Blo, ushort_t* __restrict__ S,
               int K) {
  __shared__ float smemf[128 * 65];   // 33,280 B >= 32 KB staging
  ushort_t* As = (ushort_t*)smemf;    // 128 rows x 64 k = 8192 ushorts (16 KB)
  ushort_t* Bh = As + 8192;           // 64 x 64 = 4096 (8 KB)
  ushort_t* Bl = Bh + 4096;           // 4096 (8 KB)
  float* Zt = smemf;                  // [128 t][65] padded (epilogue overlay)

  const int tid = threadIdx.x;
  const int wave = tid >> 6, lane = tid & 63;
  const int b = blockIdx.y;
  const int m0 = b * 128;
  const int o0 = blockIdx.x * 64;
  const int qm = wave >> 1, qn = wave & 1;
  const int fr = lane & 15, q = lane >> 4;

  f32x4 acc[4][2];
#pragma unroll
  for (int i = 0; i < 4; ++i)
#pragma unroll
    for (int j = 0; j < 2; ++j) acc[i][j] = (f32x4){0.f, 0.f, 0.f, 0.f};

  // staging source offsets (ushort elems). A: 1024 slots, 4 rounds/wave.
  size_t gA[4];
  ushort_t* lA[4];
#pragma unroll
  for (int r = 0; r < 4; ++r) {
    int s = wave * 256 + r * 64 + lane;
    int row = s >> 3;
    int u = (s & 7) ^ (row & 7);
    gA[r] = (size_t)(m0 + row) * K + u * 8;
    lA[r] = As + (size_t)(wave * 256 + r * 64) * 8;  // wave-uniform base
  }
  // B: 512 slots/plane, 2 rounds/wave.
  size_t gB[2];
  ushort_t *lBh[2], *lBl[2];
#pragma unroll
  for (int r = 0; r < 2; ++r) {
    int s = wave * 128 + r * 64 + lane;
    int row = s >> 3;
    int u = (s & 7) ^ (row & 7);
    gB[r] = (size_t)(o0 + row) * K + u * 8;
    lBh[r] = Bh + (size_t)(wave * 128 + r * 64) * 8;
    lBl[r] = Bl + (size_t)(wave * 128 + r * 64) * 8;
  }

  // frag LDS offsets (swizzled), per kk half
  int aoff[4][2], boff[2][2];
#pragma unroll
  for (int i = 0; i < 4; ++i)
#pragma unroll
    for (int kk = 0; kk < 2; ++kk) {
      int row = qm * 64 + i * 16 + fr;
      int u = (kk * 4 + q) ^ (row & 7);
      aoff[i][kk] = row * 64 + u * 8;
    }
#pragma unroll
  for (int j = 0; j < 2; ++j)
#pragma unroll
    for (int kk = 0; kk < 2; ++kk) {
      int row = qn * 32 + j * 16 + fr;
      int u = (kk * 4 + q) ^ (row & 7);
      boff[j][kk] = row * 64 + u * 8;
    }

  for (int kc = 0; kc < K; kc += 64) {
#pragma unroll
    for (int r = 0; r < 4; ++r) glds16(A + gA[r] + kc, lA[r]);
#pragma unroll
    for (int r = 0; r < 2; ++r) {
      glds16(Bhi + gB[r] + kc, lBh[r]);
      glds16(Blo + gB[r] + kc, lBl[r]);
    }
    __syncthreads();

#pragma unroll
    for (int kk = 0; kk < 2; ++kk) {
      bf16x8 af[4], bh[2], bl[2];
#pragma unroll
      for (int i = 0; i < 4; ++i) af[i] = *(const bf16x8*)(As + aoff[i][kk]);
#pragma unroll
      for (int j = 0; j < 2; ++j) {
        bh[j] = *(const bf16x8*)(Bh + boff[j][kk]);
        bl[j] = *(const bf16x8*)(Bl + boff[j][kk]);
      }
#pragma unroll
      for (int i = 0; i < 4; ++i)
#pragma unroll
        for (int j = 0; j < 2; ++j) {
          acc[i][j] = __builtin_amdgcn_mfma_f32_16x16x32_bf16(af[i], bh[j], acc[i][j], 0, 0, 0);
          acc[i][j] = __builtin_amdgcn_mfma_f32_16x16x32_bf16(af[i], bl[j], acc[i][j], 0, 0, 0);
        }
    }
    __syncthreads();
  }

  // acc -> LDS Z-tile: t = qm*64+i*16+q*4+rr, o-local = qn*32+j*16+fr
#pragma unroll
  for (int i = 0; i < 4; ++i)
#pragma unroll
    for (int j = 0; j < 2; ++j)
#pragma unroll
      for (int rr = 0; rr < 4; ++rr)
        Zt[(qm * 64 + i * 16 + q * 4 + rr) * 65 + qn * 32 + j * 16 + fr] = acc[i][j][rr];
  __syncthreads();

  // fused leaky-IF scan: thread tid<64 owns o-column (o0+tid)
  if (tid < 64) {
#pragma clang fp contract(off)
    float cur = 0.0f, vol = 0.0f;
    const int o = o0 + tid;
    for (int t = 0; t < 128; ++t) {
      float z = Zt[t * 65 + tid];
      cur = cur * 0.7f;
      cur = cur + z;
      vol = vol * 0.2f;
      vol = vol + cur;
      float v = vol - 1.0f;
      float s = (v >= 0.0f) ? 1.0f : 0.0f;
      vol = vol * (1.0f - s);
      S[(size_t)(m0 + t) * O_TOT + o] = (v >= 0.0f) ? 0x3F80u : 0u;
    }
  }
}

// ---------- layer 3 fused: per-b dense (O=2, fp32) + scan + output ----------
__global__ __launch_bounds__(256) void gemm3_scan(const ushort_t* __restrict__ X,
                                                  const float* __restrict__ W3,
                                                  float* __restrict__ out) {
  __shared__ float w3s[2048];
  __shared__ float z3[256];  // [t*2 + o]
  __shared__ float sp[256];  // [o*128 + t]
  const int tid = threadIdx.x;
  const int b = blockIdx.x;
  for (int i = tid; i < 2048; i += 256) w3s[i] = W3[i];
  __syncthreads();
  const int wave = tid >> 6, lane = tid & 63;
  for (int tt = 0; tt < 32; ++tt) {
    int t = wave * 32 + tt;
    const uint_t* row = (const uint_t*)(X + (size_t)(b * 128 + t) * 1024) + lane * 8;
    float s0 = 0.0f, s1 = 0.0f;
#pragma unroll
    for (int jw = 0; jw < 8; ++jw) {
      uint_t u = row[jw];
      float x0 = __uint_as_float(u << 16);
      float x1 = __uint_as_float(u & 0xFFFF0000u);
      int i0 = lane * 16 + jw * 2;
      s0 = fmaf(x0, w3s[i0], s0);
      s1 = fmaf(x0, w3s[1024 + i0], s1);
      s0 = fmaf(x1, w3s[i0 + 1], s0);
      s1 = fmaf(x1, w3s[1024 + i0 + 1], s1);
    }
#pragma unroll
    for (int off = 32; off > 0; off >>= 1) {
      s0 += __shfl_down(s0, off);
      s1 += __shfl_down(s1, off);
    }
    if (lane == 0) {
      z3[t * 2] = s0;
      z3[t * 2 + 1] = s1;
    }
  }
  __syncthreads();
  if (tid < 2) {
#pragma clang fp contract(off)
    float cur = 0.0f, vol = 0.0f;
    for (int t = 0; t < 128; ++t) {
      float z = z3[t * 2 + tid];
      cur = cur * 0.7f;
      cur = cur + z;
      vol = vol * 0.2f;
      vol = vol + cur;
      float v = vol - 1.0f;
      float s = (v >= 0.0f) ? 1.0f : 0.0f;
      vol = vol * (1.0f - s);
      sp[tid * 128 + t] = s;
    }
  }
  __syncthreads();
  out[b * 256 + tid] = sp[tid];
}

extern "C" void kernel_launch(void* const* d_in, const int* in_sizes, int n_in,
                              void* d_out, int out_size, void* d_ws, size_t ws_size,
                              hipStream_t stream) {
  const float* spike = (const float*)d_in[0];  // [64, 2048, 128]
  const float* W1 = (const float*)d_in[1];     // [1024, 2048]
  const float* W2 = (const float*)d_in[2];     // [1024, 1024]
  const float* W3 = (const float*)d_in[3];     // [2, 1024]
  float* out = (float*)d_out;                  // [64, 2, 128]

  char* ws = (char*)d_ws;
  ushort_t* A1 = (ushort_t*)ws;                                 // 32 MB
  ushort_t* S2 = (ushort_t*)(ws + (size_t)32 * 1024 * 1024);    // 16 MB
  ushort_t* S3 = (ushort_t*)(ws + (size_t)48 * 1024 * 1024);    // 16 MB
  ushort_t* W1hi = (ushort_t*)(ws + (size_t)64 * 1024 * 1024);  // 4 MB
  ushort_t* W1lo = (ushort_t*)(ws + (size_t)68 * 1024 * 1024);  // 4 MB
  ushort_t* W2hi = (ushort_t*)(ws + (size_t)72 * 1024 * 1024);  // 2 MB
  ushort_t* W2lo = (ushort_t*)(ws + (size_t)74 * 1024 * 1024);  // 2 MB

  split_w<<<12288, 256, 0, stream>>>(W1, W2, W1hi, W1lo, W2hi, W2lo);
  transpose_spike<<<dim3(64, 64), 256, 0, stream>>>(spike, A1);
  // L1: M=8192 (b*128+t), K=2048, O=1024
  gemm_scan<<<dim3(16, 64), 256, 0, stream>>>(A1, W1hi, W1lo, S2, 2048);
  // L2: K=1024
  gemm_scan<<<dim3(16, 64), 256, 0, stream>>>(S2, W2hi, W2lo, S3, 1024);
  // L3 + final scan + output
  gemm3_scan<<<64, 256, 0, stream>>>(S3, W3, out);
}